// Round 13
// baseline (122.254 us; speedup 1.0000x reference)
//
#include <hip/hip_runtime.h>

typedef unsigned short u16;
typedef unsigned int u32;
typedef __bf16 bf16x8 __attribute__((ext_vector_type(8)));
typedef float f32x4 __attribute__((ext_vector_type(4)));

// workspace layout (bytes)
#define OFF_G      0x000000   // 8*32*256 f32   (256 KB)
#define OFF_AW     0x040000   // 8*8*4096 f32   (1 MB)
#define OFF_WT     0x140000   // 256*2304 bf16  (1.125 MB)
#define OFF_SHIFT  0x260000   // 256 f32
#define OFF_XPAD   0x2F0000   // 8*66*66*256 bf16 (zero-padded NHWC)
#define XPAD_BYTES (8u*66u*66u*256u*2u)
#define WS_NEED    ((size_t)OFF_XPAD + (size_t)XPAD_BYTES)

__device__ __forceinline__ u16 f2bf(float f) {
  union { float f; u32 u; } v; v.f = f;
  return (u16)((v.u + 0x7FFFu + ((v.u >> 16) & 1u)) >> 16);
}

__device__ __forceinline__ void gl2lds16(const u16* g, u16* l) {
  __builtin_amdgcn_global_load_lds(
      (const __attribute__((address_space(1))) void*)g,
      (__attribute__((address_space(3))) void*)l, 16, 0, 0);
}

__device__ __forceinline__ bf16x8 cvt8(const float* p) {
  const float4 a = *(const float4*)p;
  const float4 b = *(const float4*)(p + 4);
  u16 t[8];
  t[0] = f2bf(a.x); t[1] = f2bf(a.y); t[2] = f2bf(a.z); t[3] = f2bf(a.w);
  t[4] = f2bf(b.x); t[5] = f2bf(b.y); t[6] = f2bf(b.z); t[7] = f2bf(b.w);
  return *(const bf16x8*)t;
}

// ---- fused: blocks 0..255 = wprep (per-co); 256..287 = MFMA guide projection ----
__global__ __launch_bounds__(256) void g2_k(
    const float* __restrict__ w, const float* __restrict__ gamma,
    const float* __restrict__ beta, const float* __restrict__ mean,
    const float* __restrict__ var, u16* __restrict__ wt, float* __restrict__ shift,
    const float* __restrict__ guide, const float* __restrict__ glw,
    const float* __restrict__ glb, float* __restrict__ g) {
  const int tid = threadIdx.x;
  if (blockIdx.x < 256) {
    const int co = blockIdx.x;
    const float inv = gamma[co] / sqrtf(var[co] + 1e-3f);
    float v[9];
#pragma unroll
    for (int t = 0; t < 9; ++t) v[t] = w[(size_t)co * 2304 + tid * 9 + t];
#pragma unroll
    for (int t = 0; t < 9; ++t) wt[co * 2304 + t * 256 + tid] = f2bf(v[t] * inv);
    if (tid == 0) shift[co] = beta[co] - mean[co] * inv;
    return;
  }
  const int bid = blockIdx.x - 256;
  const int b  = bid >> 2;
  const int e0 = (bid & 3) * 64;
  const int lane = tid & 63;
  const int wn   = tid >> 6;
  const int l15  = lane & 15;
  const int kq   = lane >> 4;

  const float* ga0 = guide + (size_t)b * 16384 + (size_t)l15 * 512 + kq * 8;
  const float* gb0 = glw + (size_t)(e0 + wn * 16 + l15) * 512 + kq * 8;

  f32x4 acc[2];
  acc[0] = (f32x4){0.f, 0.f, 0.f, 0.f};
  acc[1] = (f32x4){0.f, 0.f, 0.f, 0.f};
#pragma unroll
  for (int kc = 0; kc < 16; ++kc) {
    const int k0 = kc * 32;
    const bf16x8 bfr = cvt8(gb0 + k0);
#pragma unroll
    for (int mi = 0; mi < 2; ++mi) {
      const bf16x8 af = cvt8(ga0 + (size_t)mi * 16 * 512 + k0);
      acc[mi] = __builtin_amdgcn_mfma_f32_16x16x32_bf16(af, bfr, acc[mi], 0, 0, 0);
    }
  }
  const int e = e0 + wn * 16 + l15;
  const float bv = glb[e];
#pragma unroll
  for (int mi = 0; mi < 2; ++mi)
#pragma unroll
    for (int j = 0; j < 4; ++j) {
      const int n = mi * 16 + kq * 4 + j;
      g[(size_t)b * 8192 + n * 256 + e] = acc[mi][j] + bv;
    }
}

// ---- fused: x -> xpad bf16 + border zeros + MFMA attention weights ----
__global__ __launch_bounds__(256) void xpaw2_k(const float* __restrict__ x,
                                               const float* __restrict__ g,
                                               const float* __restrict__ bias,
                                               u16* __restrict__ xp,
                                               float* __restrict__ aw) {
  __shared__ u16 tile[256][64];
  __shared__ u16 xT[64][256];
  const int tid = threadIdx.x;
  const int b = blockIdx.x >> 6, y = blockIdx.x & 63;
  const int lane = tid & 63;
  const int wv   = tid >> 6;
  const int l15  = lane & 15;
  const int kq   = lane >> 4;

  bf16x8 af[2][2];
#pragma unroll
  for (int rep = 0; rep < 2; ++rep) {
    const int m = wv + rep * 4;
#pragma unroll
    for (int mi2 = 0; mi2 < 2; ++mi2)
      af[rep][mi2] = cvt8(g + (size_t)b * 8192 + (mi2 * 16 + l15) * 256 + m * 32 + kq * 8);
  }

  {
    const int cb = tid >> 4, xq = tid & 15;
#pragma unroll
    for (int i = 0; i < 16; ++i) {
      const int c = i * 16 + cb;
      const float4 v = *(const float4*)(x + (size_t)(b * 256 + c) * 4096 + y * 64 + xq * 4);
      ushort4 o; o.x = f2bf(v.x); o.y = f2bf(v.y); o.z = f2bf(v.z); o.w = f2bf(v.w);
      *(ushort4*)(&tile[c][xq * 4]) = o;
    }
  }
  __syncthreads();

  const int px = tid & 63, cg = tid >> 6;
  {
    u32 wbuf[32];
#pragma unroll
    for (int j = 0; j < 32; ++j) {
      const u16 lo = tile[cg * 64 + 2 * j][px];
      const u16 hi = tile[cg * 64 + 2 * j + 1][px];
      wbuf[j] = (u32)lo | ((u32)hi << 16);
    }
    u16* dst = xp + ((size_t)(b * 66 + y + 1) * 66 + px + 1) * 256 + cg * 64;
#pragma unroll
    for (int q = 0; q < 8; ++q) {
      uint4 v; v.x = wbuf[q * 4]; v.y = wbuf[q * 4 + 1]; v.z = wbuf[q * 4 + 2]; v.w = wbuf[q * 4 + 3];
      *(uint4*)(dst + q * 8) = v;
      const int slot = (cg * 8 + q) ^ (px & 7);
      *(uint4*)(&xT[px][slot * 8]) = v;
    }
  }
  {
    uint4* rowbase = (uint4*)(xp + (size_t)(b * 66 + y + 1) * 66 * 256);
    if (tid < 32) rowbase[tid] = (uint4){0, 0, 0, 0};
    else if (tid < 64) rowbase[65 * 32 + (tid - 32)] = (uint4){0, 0, 0, 0};
    if (y == 0) {
      uint4* r0 = (uint4*)(xp + (size_t)(b * 66) * 66 * 256);
      for (int i = tid; i < 2112; i += 256) r0[i] = (uint4){0, 0, 0, 0};
    }
    if (y == 63) {
      uint4* r65 = (uint4*)(xp + (size_t)(b * 66 + 65) * 66 * 256);
      for (int i = tid; i < 2112; i += 256) r65[i] = (uint4){0, 0, 0, 0};
    }
  }
  __syncthreads();

#pragma unroll
  for (int rep = 0; rep < 2; ++rep) {
    const int m = wv + rep * 4;
    bf16x8 bfr[4];
#pragma unroll
    for (int ni2 = 0; ni2 < 4; ++ni2) {
      const int row = ni2 * 16 + l15;
      const int slot = (m * 4 + kq) ^ (row & 7);
      bfr[ni2] = *(const bf16x8*)(&xT[row][slot * 8]);
    }
    f32x4 acc[2][4];
#pragma unroll
    for (int i = 0; i < 2; ++i)
#pragma unroll
      for (int j = 0; j < 4; ++j) acc[i][j] = (f32x4){0.f, 0.f, 0.f, 0.f};
#pragma unroll
    for (int mi2 = 0; mi2 < 2; ++mi2)
#pragma unroll
      for (int ni2 = 0; ni2 < 4; ++ni2)
        acc[mi2][ni2] = __builtin_amdgcn_mfma_f32_16x16x32_bf16(af[rep][mi2], bfr[ni2], acc[mi2][ni2], 0, 0, 0);

    const float bm = bias[m];
#pragma unroll
    for (int ni2 = 0; ni2 < 4; ++ni2) {
      float v = acc[0][ni2][0];
#pragma unroll
      for (int j = 1; j < 4; ++j) v = fmaxf(v, acc[0][ni2][j]);
#pragma unroll
      for (int j = 0; j < 4; ++j) v = fmaxf(v, acc[1][ni2][j]);
      v = fmaxf(v, __shfl_xor(v, 16));
      v = fmaxf(v, __shfl_xor(v, 32));
      const float z = v * 0.17677669529663687f + bm;
      const float a = 1.f / (1.f + expf(-z));
      if (kq == 0)
        aw[(size_t)(b * 8 + m) * 4096 + y * 64 + ni2 * 16 + l15] = a;
    }
  }
}

// ---- standalone attnw (fallback path only) ----
__global__ void attnw_k(const float* __restrict__ x, const float* __restrict__ g,
                        const float* __restrict__ bias, float* __restrict__ aw) {
  const int bm = blockIdx.x;
  const int b = bm >> 3, m = bm & 7;
  const int p = blockIdx.y * 256 + threadIdx.x;
  const float* xp = x + (size_t)(b * 256 + m * 32) * 4096 + p;
  float xv[32];
#pragma unroll
  for (int c = 0; c < 32; ++c) xv[c] = xp[(size_t)c * 4096];
  const float* gv = g + b * 8192 + m * 32;
  float best = -3.4e38f;
#pragma unroll 4
  for (int n = 0; n < 32; ++n) {
    const float* grow = gv + n * 256;
    float s = 0.f;
#pragma unroll
    for (int c = 0; c < 32; ++c) s = fmaf(xv[c], grow[c], s);
    best = fmaxf(best, s);
  }
  const float z = best * 0.17677669529663687f + bias[m];
  aw[(size_t)bm * 4096 + p] = 1.f / (1.f + expf(-z));
}

// ---- conv 3x3 implicit GEMM: 8-wave 128co x 256px.
//      A (weights) from L2 via register prefetch (no LDS); B triple-buffered LDS.
//      LDS traffic/chunk 112KB -> 64KB. Head vmcnt counts 12 issues/chunk. ----
#define B_U16 16384

#define STAGE_B(bof, bb) do {                                              \
    _Pragma("unroll")                                                      \
    for (int q_ = 0; q_ < 4; ++q_)                                         \
      gl2lds16(bxt + (ptrdiff_t)q_ * 16896 + (bof), (bb) + wv * 512 + q_ * 4096); \
  } while (0)

// load 8 A-frags (mi 0..3, ks 0..1) for chunk k-offset koff into dst[8]
#define LOAD_A(koff, dst) do {                                             \
    _Pragma("unroll")                                                      \
    for (int mi_ = 0; mi_ < 4; ++mi_)                                      \
      _Pragma("unroll")                                                    \
      for (int ks_ = 0; ks_ < 2; ++ks_)                                    \
        (dst)[mi_ * 2 + ks_] = *(const bf16x8*)(awt0 + (size_t)mi_ * 36864 \
                                                + (koff) + ks_ * 32);      \
  } while (0)

__global__ __launch_bounds__(512, 2) void conv8e_k(
    const u16* __restrict__ xp, const u16* __restrict__ wt,
    const float* __restrict__ shift, const float* __restrict__ aw,
    float* __restrict__ out) {
  __shared__ u16 lds[3 * B_U16];

  const int tid  = threadIdx.x;          // 0..511
  const int lane = tid & 63;
  const int wv   = tid >> 6;             // 0..7
  const int wm   = wv >> 2;              // 0..1 (co half)
  const int wn   = wv & 3;               // 0..3 (px quarter)

  const int pxt = blockIdx.x;            // 0..127 pixel tile
  const int co0 = blockIdx.y * 128;
  const int p0  = pxt * 256;
  const int b   = pxt >> 4;
  const int y0  = (pxt & 15) * 4;

  // B staging: swizzled source, linear dest (rule 21)
  const int sr    = tid >> 3;                    // 0..63
  const int sslot = (tid & 7) ^ (sr & 7);
  const u16* bxt = xp + ((size_t)(b * 66 + y0 + 1) * 66 + sr + 1) * 256 + sslot * 8;

  const int l15 = lane & 15;
  const int sx  = lane & 7;
  const int kq  = lane >> 4;
  // A base: row (co0 + wm*64 + l15), frag mi adds 16 rows (16*2304=36864 elems)
  const u16* awt0 = wt + (size_t)(co0 + wm * 64 + l15) * 2304 + kq * 8;
  const int bRowB = (wn * 64 + l15) * 128;

  u16* bR  = lds;
  u16* bN1 = lds + B_U16;
  u16* bN2 = lds + 2 * B_U16;

  f32x4 acc[4][4];
#pragma unroll
  for (int i = 0; i < 4; ++i)
#pragma unroll
    for (int j = 0; j < 4; ++j) acc[i][j] = (f32x4){0.f, 0.f, 0.f, 0.f};

  bf16x8 aA[8], aB[8];   // even chunks compute from aA, odd from aB (static idx)

  // prologue: B(0), B(1), A(0). t=0 tap bof = ((-1)*66 + (-1))*256 = -17152
  STAGE_B(-17152,      bR);
  STAGE_B(-17152 + 64, bN1);
  LOAD_A(0, aA);

  int kbase = 0;   // t*256
  for (int t = 0; t < 9; ++t) {
    const int bof_c = ((t / 3 - 1) * 66 + (t % 3 - 1)) * 256;
    const int t1 = t + 1;
    const int bof_n = (t1 < 9) ? ((t1 / 3 - 1) * 66 + (t1 % 3 - 1)) * 256 : 0;
#pragma unroll
    for (int q = 0; q < 4; ++q) {
      // ---- head: ensure B(c) landed. youngers(B(c)) = 20 steady, 12 first, 16 last
      if (t == 0 && q == 0) {
        asm volatile("s_waitcnt vmcnt(12)" ::: "memory");
      } else if (t == 8 && q == 3) {
        asm volatile("s_waitcnt vmcnt(16)" ::: "memory");
      } else {
        asm volatile("s_waitcnt vmcnt(20)" ::: "memory");
      }
      __builtin_amdgcn_s_barrier();
      __builtin_amdgcn_sched_barrier(0);

      // ---- stage B(c+2) ----
      if ((t < 8) || (q < 2)) {
        const int bsoff = (q < 2) ? (bof_c + (q + 2) * 64) : (bof_n + (q - 2) * 64);
        STAGE_B(bsoff, bN2);
      }
      // ---- prefetch A(c+1) into the other reg buffer ----
      if ((t < 8) || (q < 3)) {
        const int koff_n = (q < 3) ? (kbase + (q + 1) * 64) : (kbase + 256);
        if ((q & 1) == 0) { LOAD_A(koff_n, aB); } else { LOAD_A(koff_n, aA); }
      }
      __builtin_amdgcn_sched_barrier(0);

      // ---- compute chunk c from regs + bR ----
      const char* Bc = (const char*)bR;
#pragma unroll
      for (int ks = 0; ks < 2; ++ks) {
        const int slotb = ((((ks << 2) | kq) ^ sx) << 4);
        bf16x8 bfr[4];
#pragma unroll
        for (int ni = 0; ni < 4; ++ni)
          bfr[ni] = *(const bf16x8*)(Bc + bRowB + ni * 2048 + slotb);
        __builtin_amdgcn_s_setprio(1);
        if ((q & 1) == 0) {
#pragma unroll
          for (int mi = 0; mi < 4; ++mi)
#pragma unroll
            for (int ni = 0; ni < 4; ++ni)
              acc[mi][ni] = __builtin_amdgcn_mfma_f32_16x16x32_bf16(aA[mi * 2 + ks], bfr[ni], acc[mi][ni], 0, 0, 0);
        } else {
#pragma unroll
          for (int mi = 0; mi < 4; ++mi)
#pragma unroll
            for (int ni = 0; ni < 4; ++ni)
              acc[mi][ni] = __builtin_amdgcn_mfma_f32_16x16x32_bf16(aB[mi * 2 + ks], bfr[ni], acc[mi][ni], 0, 0, 0);
        }
        __builtin_amdgcn_s_setprio(0);
      }

      __builtin_amdgcn_sched_barrier(0);
      __builtin_amdgcn_s_barrier();

      u16* tb = bR; bR = bN1; bN1 = bN2; bN2 = tb;
    }
    kbase += 256;
  }

  // ---- epilogue: out = (conv + shift) * aw ----
  const int pybase = p0 & 4095;
#pragma unroll
  for (int mi = 0; mi < 4; ++mi) {
#pragma unroll
    for (int j = 0; j < 4; ++j) {
      const int co = co0 + wm * 64 + mi * 16 + ((lane >> 4) << 2) + j;
      const float sh = shift[co];
      const float* awrow = aw + (size_t)(b * 8 + (co >> 5)) * 4096 + pybase;
      float* orow = out + (size_t)(b * 256 + co) * 4096 + pybase;
#pragma unroll
      for (int ni = 0; ni < 4; ++ni) {
        const int pp = wn * 64 + ni * 16 + l15;
        orow[pp] = (acc[mi][ni][j] + sh) * awrow[pp];
      }
    }
  }
}

// ---- fallback conv (f32 direct reads, predicated) if ws too small for xpad ----
#define LDK 72
__global__ __launch_bounds__(256) void conv_fb(
    const float* __restrict__ xf, const u16* __restrict__ wt,
    const float* __restrict__ shift, const float* __restrict__ aw,
    float* __restrict__ out) {
  __shared__ u16 As[128 * LDK];
  __shared__ u16 Bs[128 * LDK];
  const int tid  = threadIdx.x;
  const int lane = tid & 63;
  const int wave = tid >> 6;
  const int wm = wave >> 1, wn = wave & 1;
  const int p0  = blockIdx.x * 128;
  const int co0 = blockIdx.y * 128;
  const int b   = p0 >> 12;
  const int y0  = (p0 >> 6) & 63;
  const int bn   = tid & 127;
  const int half = tid >> 7;
  const int py = y0 + (bn >> 6);
  const int px = bn & 63;
  const long xbase = (long)b * (256L * 4096L);
  const int arow0 = tid >> 3;
  const int akc   = tid & 7;

  f32x4 acc[4][4];
#pragma unroll
  for (int i = 0; i < 4; ++i)
#pragma unroll
    for (int j = 0; j < 4; ++j) acc[i][j] = (f32x4){0.f, 0.f, 0.f, 0.f};

  for (int t = 0; t < 9; ++t) {
    const int dy = t / 3 - 1, dxx = t % 3 - 1;
    const int yy = py + dy, xg = px + dxx;
    const bool valid = ((unsigned)yy < 64u) && ((unsigned)xg < 64u);
    const long pixoff = xbase + (long)yy * 64 + xg;
    for (int ci0 = 0; ci0 < 256; ci0 += 64) {
      const int kbase = t * 256 + ci0;
#pragma unroll
      for (int q = 0; q < 4; ++q) {
        const int row = arow0 + q * 32;
        const uint4 v = *(const uint4*)(wt + (size_t)(co0 + row) * 2304 + kbase + akc * 8);
        *(uint4*)(&As[row * LDK + akc * 8]) = v;
      }
      {
        u32 vals[16];
        const int chb = ci0 + half * 32;
#pragma unroll
        for (int jj = 0; jj < 16; ++jj) {
          const float lo = valid ? xf[pixoff + (long)(chb + jj * 2) * 4096] : 0.f;
          const float hi = valid ? xf[pixoff + (long)(chb + jj * 2 + 1) * 4096] : 0.f;
          vals[jj] = (u32)f2bf(lo) | ((u32)f2bf(hi) << 16);
        }
#pragma unroll
        for (int q = 0; q < 4; ++q) {
          uint4 v; v.x = vals[q*4]; v.y = vals[q*4+1]; v.z = vals[q*4+2]; v.w = vals[q*4+3];
          *(uint4*)(&Bs[bn * LDK + half * 32 + q * 8]) = v;
        }
      }
      __syncthreads();
#pragma unroll
      for (int ks = 0; ks < 2; ++ks) {
        const int coloff = ks * 32 + (lane >> 4) * 8;
        bf16x8 af[4], bfr[4];
#pragma unroll
        for (int mi = 0; mi < 4; ++mi)
          af[mi] = *(const bf16x8*)(&As[(wm * 64 + mi * 16 + (lane & 15)) * LDK + coloff]);
#pragma unroll
        for (int ni = 0; ni < 4; ++ni)
          bfr[ni] = *(const bf16x8*)(&Bs[(wn * 64 + ni * 16 + (lane & 15)) * LDK + coloff]);
#pragma unroll
        for (int mi = 0; mi < 4; ++mi)
#pragma unroll
          for (int ni = 0; ni < 4; ++ni)
            acc[mi][ni] = __builtin_amdgcn_mfma_f32_16x16x32_bf16(af[mi], bfr[ni], acc[mi][ni], 0, 0, 0);
      }
      __syncthreads();
    }
  }
  const int pybase = p0 & 4095;
#pragma unroll
  for (int mi = 0; mi < 4; ++mi) {
#pragma unroll
    for (int j = 0; j < 4; ++j) {
      const int co = co0 + wm * 64 + mi * 16 + ((lane >> 4) << 2) + j;
      const float sh = shift[co];
      const float* awrow = aw + (size_t)(b * 8 + (co >> 5)) * 4096 + pybase;
      float* orow = out + (size_t)(b * 256 + co) * 4096 + pybase;
#pragma unroll
      for (int ni = 0; ni < 4; ++ni) {
        const int pp = wn * 64 + ni * 16 + (lane & 15);
        orow[pp] = (acc[mi][ni][j] + sh) * awrow[pp];
      }
    }
  }
}

extern "C" void kernel_launch(void* const* d_in, const int* in_sizes, int n_in,
                              void* d_out, int out_size, void* d_ws, size_t ws_size,
                              hipStream_t stream) {
  (void)in_sizes; (void)n_in; (void)out_size;
  const float* x     = (const float*)d_in[0];
  const float* guide = (const float*)d_in[1];
  const float* glw   = (const float*)d_in[2];
  const float* glb   = (const float*)d_in[3];
  const float* bias  = (const float*)d_in[4];
  const float* pw    = (const float*)d_in[5];
  const float* gamma = (const float*)d_in[6];
  const float* beta  = (const float*)d_in[7];
  const float* mean  = (const float*)d_in[8];
  const float* var   = (const float*)d_in[9];
  float* out = (float*)d_out;

  char* ws = (char*)d_ws;
  float* g     = (float*)(ws + OFF_G);
  float* aw    = (float*)(ws + OFF_AW);
  u16*   wt    = (u16*)(ws + OFF_WT);
  float* shift = (float*)(ws + OFF_SHIFT);
  u16*   xpad  = (u16*)(ws + OFF_XPAD);
  const int usexp = (ws_size >= WS_NEED) ? 1 : 0;

  g2_k<<<dim3(288), dim3(256), 0, stream>>>(pw, gamma, beta, mean, var, wt, shift,
                                            guide, glw, glb, g);
  if (usexp) {
    xpaw2_k<<<dim3(512), dim3(256), 0, stream>>>(x, g, bias, xpad, aw);
    conv8e_k<<<dim3(128, 2), dim3(512), 0, stream>>>(xpad, wt, shift, aw, out);
  } else {
    attnw_k<<<dim3(64, 16), dim3(256), 0, stream>>>(x, g, bias, aw);
    conv_fb<<<dim3(256, 2), dim3(256), 0, stream>>>(x, wt, shift, aw, out);
  }
}

// Round 14
// 71.160 us; speedup vs baseline: 1.7180x; 1.7180x over previous
//
#include <hip/hip_runtime.h>

typedef unsigned short u16;
typedef unsigned int u32;
typedef __bf16 bf16x8 __attribute__((ext_vector_type(8)));
typedef float f32x4 __attribute__((ext_vector_type(4)));

// workspace layout (bytes)
#define OFF_G      0x000000   // 8*32*256 f32   (256 KB)
#define OFF_AW     0x040000   // 8*8*4096 f32   (1 MB)
#define OFF_WT     0x140000   // 256*2304 bf16  (1.125 MB)
#define OFF_SHIFT  0x260000   // 256 f32
#define OFF_XPAD   0x2F0000   // 8*66*66*256 bf16 (zero-padded NHWC)
#define XPAD_BYTES (8u*66u*66u*256u*2u)
#define WS_NEED    ((size_t)OFF_XPAD + (size_t)XPAD_BYTES)

__device__ __forceinline__ u16 f2bf(float f) {
  union { float f; u32 u; } v; v.f = f;
  return (u16)((v.u + 0x7FFFu + ((v.u >> 16) & 1u)) >> 16);
}

__device__ __forceinline__ void gl2lds16(const u16* g, u16* l) {
  __builtin_amdgcn_global_load_lds(
      (const __attribute__((address_space(1))) void*)g,
      (__attribute__((address_space(3))) void*)l, 16, 0, 0);
}

__device__ __forceinline__ bf16x8 cvt8(const float* p) {
  const float4 a = *(const float4*)p;
  const float4 b = *(const float4*)(p + 4);
  u16 t[8];
  t[0] = f2bf(a.x); t[1] = f2bf(a.y); t[2] = f2bf(a.z); t[3] = f2bf(a.w);
  t[4] = f2bf(b.x); t[5] = f2bf(b.y); t[6] = f2bf(b.z); t[7] = f2bf(b.w);
  return *(const bf16x8*)t;
}

// ---- fused: blocks 0..255 = wprep (per-co); 256..287 = MFMA guide projection ----
__global__ __launch_bounds__(256) void g2_k(
    const float* __restrict__ w, const float* __restrict__ gamma,
    const float* __restrict__ beta, const float* __restrict__ mean,
    const float* __restrict__ var, u16* __restrict__ wt, float* __restrict__ shift,
    const float* __restrict__ guide, const float* __restrict__ glw,
    const float* __restrict__ glb, float* __restrict__ g) {
  const int tid = threadIdx.x;
  if (blockIdx.x < 256) {
    const int co = blockIdx.x;
    const float inv = gamma[co] / sqrtf(var[co] + 1e-3f);
    float v[9];
#pragma unroll
    for (int t = 0; t < 9; ++t) v[t] = w[(size_t)co * 2304 + tid * 9 + t];
#pragma unroll
    for (int t = 0; t < 9; ++t) wt[co * 2304 + t * 256 + tid] = f2bf(v[t] * inv);
    if (tid == 0) shift[co] = beta[co] - mean[co] * inv;
    return;
  }
  const int bid = blockIdx.x - 256;
  const int b  = bid >> 2;
  const int e0 = (bid & 3) * 64;
  const int lane = tid & 63;
  const int wn   = tid >> 6;
  const int l15  = lane & 15;
  const int kq   = lane >> 4;

  const float* ga0 = guide + (size_t)b * 16384 + (size_t)l15 * 512 + kq * 8;
  const float* gb0 = glw + (size_t)(e0 + wn * 16 + l15) * 512 + kq * 8;

  f32x4 acc[2];
  acc[0] = (f32x4){0.f, 0.f, 0.f, 0.f};
  acc[1] = (f32x4){0.f, 0.f, 0.f, 0.f};
#pragma unroll
  for (int kc = 0; kc < 16; ++kc) {
    const int k0 = kc * 32;
    const bf16x8 bfr = cvt8(gb0 + k0);
#pragma unroll
    for (int mi = 0; mi < 2; ++mi) {
      const bf16x8 af = cvt8(ga0 + (size_t)mi * 16 * 512 + k0);
      acc[mi] = __builtin_amdgcn_mfma_f32_16x16x32_bf16(af, bfr, acc[mi], 0, 0, 0);
    }
  }
  const int e = e0 + wn * 16 + l15;
  const float bv = glb[e];
#pragma unroll
  for (int mi = 0; mi < 2; ++mi)
#pragma unroll
    for (int j = 0; j < 4; ++j) {
      const int n = mi * 16 + kq * 4 + j;
      g[(size_t)b * 8192 + n * 256 + e] = acc[mi][j] + bv;
    }
}

// ---- fused: x -> xpad bf16 + border zeros + MFMA attention weights ----
// LDS: tile[256c][64px] 32KB + xT[64px][256c] 32KB (swizzled) = 64KB -> 2 blk/CU
__global__ __launch_bounds__(256) void xpaw2_k(const float* __restrict__ x,
                                               const float* __restrict__ g,
                                               const float* __restrict__ bias,
                                               u16* __restrict__ xp,
                                               float* __restrict__ aw) {
  __shared__ u16 tile[256][64];
  __shared__ u16 xT[64][256];
  const int tid = threadIdx.x;
  const int b = blockIdx.x >> 6, y = blockIdx.x & 63;
  const int lane = tid & 63;
  const int wv   = tid >> 6;
  const int l15  = lane & 15;
  const int kq   = lane >> 4;

  bf16x8 af[2][2];
#pragma unroll
  for (int rep = 0; rep < 2; ++rep) {
    const int m = wv + rep * 4;
#pragma unroll
    for (int mi2 = 0; mi2 < 2; ++mi2)
      af[rep][mi2] = cvt8(g + (size_t)b * 8192 + (mi2 * 16 + l15) * 256 + m * 32 + kq * 8);
  }

  {
    const int cb = tid >> 4, xq = tid & 15;
#pragma unroll
    for (int i = 0; i < 16; ++i) {
      const int c = i * 16 + cb;
      const float4 v = *(const float4*)(x + (size_t)(b * 256 + c) * 4096 + y * 64 + xq * 4);
      ushort4 o; o.x = f2bf(v.x); o.y = f2bf(v.y); o.z = f2bf(v.z); o.w = f2bf(v.w);
      *(ushort4*)(&tile[c][xq * 4]) = o;
    }
  }
  __syncthreads();

  const int px = tid & 63, cg = tid >> 6;
  {
    u32 wbuf[32];
#pragma unroll
    for (int j = 0; j < 32; ++j) {
      const u16 lo = tile[cg * 64 + 2 * j][px];
      const u16 hi = tile[cg * 64 + 2 * j + 1][px];
      wbuf[j] = (u32)lo | ((u32)hi << 16);
    }
    u16* dst = xp + ((size_t)(b * 66 + y + 1) * 66 + px + 1) * 256 + cg * 64;
#pragma unroll
    for (int q = 0; q < 8; ++q) {
      uint4 v; v.x = wbuf[q * 4]; v.y = wbuf[q * 4 + 1]; v.z = wbuf[q * 4 + 2]; v.w = wbuf[q * 4 + 3];
      *(uint4*)(dst + q * 8) = v;
      const int slot = (cg * 8 + q) ^ (px & 7);   // 16B-slot XOR swizzle
      *(uint4*)(&xT[px][slot * 8]) = v;
    }
  }
  {
    uint4* rowbase = (uint4*)(xp + (size_t)(b * 66 + y + 1) * 66 * 256);
    if (tid < 32) rowbase[tid] = (uint4){0, 0, 0, 0};
    else if (tid < 64) rowbase[65 * 32 + (tid - 32)] = (uint4){0, 0, 0, 0};
    if (y == 0) {
      uint4* r0 = (uint4*)(xp + (size_t)(b * 66) * 66 * 256);
      for (int i = tid; i < 2112; i += 256) r0[i] = (uint4){0, 0, 0, 0};
    }
    if (y == 63) {
      uint4* r65 = (uint4*)(xp + (size_t)(b * 66 + 65) * 66 * 256);
      for (int i = tid; i < 2112; i += 256) r65[i] = (uint4){0, 0, 0, 0};
    }
  }
  __syncthreads();

#pragma unroll
  for (int rep = 0; rep < 2; ++rep) {
    const int m = wv + rep * 4;
    bf16x8 bfr[4];
#pragma unroll
    for (int ni2 = 0; ni2 < 4; ++ni2) {
      const int row = ni2 * 16 + l15;
      const int slot = (m * 4 + kq) ^ (row & 7);
      bfr[ni2] = *(const bf16x8*)(&xT[row][slot * 8]);
    }
    f32x4 acc[2][4];
#pragma unroll
    for (int i = 0; i < 2; ++i)
#pragma unroll
      for (int j = 0; j < 4; ++j) acc[i][j] = (f32x4){0.f, 0.f, 0.f, 0.f};
#pragma unroll
    for (int mi2 = 0; mi2 < 2; ++mi2)
#pragma unroll
      for (int ni2 = 0; ni2 < 4; ++ni2)
        acc[mi2][ni2] = __builtin_amdgcn_mfma_f32_16x16x32_bf16(af[rep][mi2], bfr[ni2], acc[mi2][ni2], 0, 0, 0);

    const float bm = bias[m];
#pragma unroll
    for (int ni2 = 0; ni2 < 4; ++ni2) {
      float v = acc[0][ni2][0];
#pragma unroll
      for (int j = 1; j < 4; ++j) v = fmaxf(v, acc[0][ni2][j]);
#pragma unroll
      for (int j = 0; j < 4; ++j) v = fmaxf(v, acc[1][ni2][j]);
      v = fmaxf(v, __shfl_xor(v, 16));
      v = fmaxf(v, __shfl_xor(v, 32));
      const float z = v * 0.17677669529663687f + bm;
      const float a = 1.f / (1.f + expf(-z));
      if (kq == 0)
        aw[(size_t)(b * 8 + m) * 4096 + y * 64 + ni2 * 16 + l15] = a;
    }
  }
}

// ---- standalone attnw (fallback path only) ----
__global__ void attnw_k(const float* __restrict__ x, const float* __restrict__ g,
                        const float* __restrict__ bias, float* __restrict__ aw) {
  const int bm = blockIdx.x;
  const int b = bm >> 3, m = bm & 7;
  const int p = blockIdx.y * 256 + threadIdx.x;
  const float* xp = x + (size_t)(b * 256 + m * 32) * 4096 + p;
  float xv[32];
#pragma unroll
  for (int c = 0; c < 32; ++c) xv[c] = xp[(size_t)c * 4096];
  const float* gv = g + b * 8192 + m * 32;
  float best = -3.4e38f;
#pragma unroll 4
  for (int n = 0; n < 32; ++n) {
    const float* grow = gv + n * 256;
    float s = 0.f;
#pragma unroll
    for (int c = 0; c < 32; ++c) s = fmaf(xv[c], grow[c], s);
    best = fmaxf(best, s);
  }
  const float z = best * 0.17677669529663687f + bias[m];
  aw[(size_t)bm * 4096 + p] = 1.f / (1.f + expf(-z));
}

// ---- conv 3x3 implicit GEMM: measured-best (44.5us, MfmaUtil 32%, 0 conflicts).
//      8-wave 128co x 256px, BK=64, triple-buffer LDS, counted vmcnt pipeline. ----
#define A_U16 8192
#define B_U16 16384
#define BUF_U16 24576

#define STAGE8(koff, bof, ab, bb) do {                                     \
    _Pragma("unroll")                                                      \
    for (int q_ = 0; q_ < 2; ++q_)                                         \
      gl2lds16(awt + (size_t)q_ * 147456 + (koff), (ab) + wv * 512 + q_ * 4096); \
    _Pragma("unroll")                                                      \
    for (int q_ = 0; q_ < 4; ++q_)                                         \
      gl2lds16(bxt + (ptrdiff_t)q_ * 16896 + (bof), (bb) + wv * 512 + q_ * 4096); \
  } while (0)

__global__ __launch_bounds__(512) void conv8c_k(
    const u16* __restrict__ xp, const u16* __restrict__ wt,
    const float* __restrict__ shift, const float* __restrict__ aw,
    float* __restrict__ out) {
  __shared__ u16 lds[3 * BUF_U16];

  const int tid  = threadIdx.x;          // 0..511
  const int lane = tid & 63;
  const int wv   = tid >> 6;             // 0..7
  const int wm   = wv >> 2;              // 0..1 (co half)
  const int wn   = wv & 3;               // 0..3 (px quarter)

  const int pxt = blockIdx.x;            // 0..127 pixel tile
  const int co0 = blockIdx.y * 128;
  const int p0  = pxt * 256;
  const int b   = pxt >> 4;
  const int y0  = (pxt & 15) * 4;

  const int sr    = tid >> 3;                    // 0..63
  const int sslot = (tid & 7) ^ (sr & 7);        // rule 21: swizzle source, linear dest
  const u16* awt = wt + (size_t)(co0 + sr) * 2304 + sslot * 8;
  const u16* bxt = xp + ((size_t)(b * 66 + y0 + 1) * 66 + sr + 1) * 256 + sslot * 8;

  u16* aR  = lds;              u16* bR  = lds + A_U16;
  u16* aN1 = lds + BUF_U16;    u16* bN1 = lds + BUF_U16 + A_U16;
  u16* aN2 = lds + 2*BUF_U16;  u16* bN2 = lds + 2*BUF_U16 + A_U16;

  const int l15 = lane & 15;
  const int sx  = lane & 7;
  const int kq  = lane >> 4;
  const int aRowB = (wm * 64 + l15) * 128;
  const int bRowB = (wn * 64 + l15) * 128;

  f32x4 acc[4][4];
#pragma unroll
  for (int i = 0; i < 4; ++i)
#pragma unroll
    for (int j = 0; j < 4; ++j) acc[i][j] = (f32x4){0.f, 0.f, 0.f, 0.f};

  STAGE8(0,  -17152,      aR,  bR);   // t=0 tap: bof = ((-1)*66 + (-1))*256
  STAGE8(64, -17152 + 64, aN1, bN1);

  int kbase = 0;   // t*256
  for (int t = 0; t < 9; ++t) {
    const int bof_c = ((t / 3 - 1) * 66 + (t % 3 - 1)) * 256;
    const int t1 = t + 1;
    const int bof_n = (t1 < 9) ? ((t1 / 3 - 1) * 66 + (t1 % 3 - 1)) * 256 : 0;
#pragma unroll
    for (int q = 0; q < 4; ++q) {
      // ---- head: chunk c's 6 loads landed (issued 2 iterations ago) ----
      if (t == 8 && q == 3) {
        asm volatile("s_waitcnt vmcnt(0)" ::: "memory");   // final chunk: drain
      } else {
        asm volatile("s_waitcnt vmcnt(6)" ::: "memory");   // c done; c+1 in flight
      }
      __builtin_amdgcn_s_barrier();
      __builtin_amdgcn_sched_barrier(0);

      // ---- stage chunk c+2 (overlaps with compute below) ----
      if ((t < 8) || (q < 2)) {
        const int ksoff = kbase + (q + 2) * 64;
        const int bsoff = (q < 2) ? (bof_c + (q + 2) * 64) : (bof_n + (q - 2) * 64);
        STAGE8(ksoff, bsoff, aN2, bN2);
      }

      // ---- compute chunk c from aR/bR ----
      const char* Ac = (const char*)aR;
      const char* Bc = (const char*)bR;
#pragma unroll
      for (int ks = 0; ks < 2; ++ks) {
        const int slotb = ((((ks << 2) | kq) ^ sx) << 4);
        bf16x8 af[4], bfr[4];
#pragma unroll
        for (int mi = 0; mi < 4; ++mi)
          af[mi] = *(const bf16x8*)(Ac + aRowB + mi * 2048 + slotb);
#pragma unroll
        for (int ni = 0; ni < 4; ++ni)
          bfr[ni] = *(const bf16x8*)(Bc + bRowB + ni * 2048 + slotb);
        __builtin_amdgcn_s_setprio(1);
#pragma unroll
        for (int mi = 0; mi < 4; ++mi)
#pragma unroll
          for (int ni = 0; ni < 4; ++ni)
            acc[mi][ni] = __builtin_amdgcn_mfma_f32_16x16x32_bf16(af[mi], bfr[ni], acc[mi][ni], 0, 0, 0);
        __builtin_amdgcn_s_setprio(0);
      }

      __builtin_amdgcn_sched_barrier(0);
      __builtin_amdgcn_s_barrier();

      u16* ta = aR; aR = aN1; aN1 = aN2; aN2 = ta;
      u16* tb = bR; bR = bN1; bN1 = bN2; bN2 = tb;
    }
    kbase += 256;
  }

  // ---- epilogue: out = (conv + shift) * aw ----
  const int pybase = p0 & 4095;
#pragma unroll
  for (int mi = 0; mi < 4; ++mi) {
#pragma unroll
    for (int j = 0; j < 4; ++j) {
      const int co = co0 + wm * 64 + mi * 16 + ((lane >> 4) << 2) + j;
      const float sh = shift[co];
      const float* awrow = aw + (size_t)(b * 8 + (co >> 5)) * 4096 + pybase;
      float* orow = out + (size_t)(b * 256 + co) * 4096 + pybase;
#pragma unroll
      for (int ni = 0; ni < 4; ++ni) {
        const int pp = wn * 64 + ni * 16 + l15;
        orow[pp] = (acc[mi][ni][j] + sh) * awrow[pp];
      }
    }
  }
}

// ---- fallback conv (f32 direct reads, predicated) if ws too small for xpad ----
#define LDK 72
__global__ __launch_bounds__(256) void conv_fb(
    const float* __restrict__ xf, const u16* __restrict__ wt,
    const float* __restrict__ shift, const float* __restrict__ aw,
    float* __restrict__ out) {
  __shared__ u16 As[128 * LDK];
  __shared__ u16 Bs[128 * LDK];
  const int tid  = threadIdx.x;
  const int lane = tid & 63;
  const int wave = tid >> 6;
  const int wm = wave >> 1, wn = wave & 1;
  const int p0  = blockIdx.x * 128;
  const int co0 = blockIdx.y * 128;
  const int b   = p0 >> 12;
  const int y0  = (p0 >> 6) & 63;
  const int bn   = tid & 127;
  const int half = tid >> 7;
  const int py = y0 + (bn >> 6);
  const int px = bn & 63;
  const long xbase = (long)b * (256L * 4096L);
  const int arow0 = tid >> 3;
  const int akc   = tid & 7;

  f32x4 acc[4][4];
#pragma unroll
  for (int i = 0; i < 4; ++i)
#pragma unroll
    for (int j = 0; j < 4; ++j) acc[i][j] = (f32x4){0.f, 0.f, 0.f, 0.f};

  for (int t = 0; t < 9; ++t) {
    const int dy = t / 3 - 1, dxx = t % 3 - 1;
    const int yy = py + dy, xg = px + dxx;
    const bool valid = ((unsigned)yy < 64u) && ((unsigned)xg < 64u);
    const long pixoff = xbase + (long)yy * 64 + xg;
    for (int ci0 = 0; ci0 < 256; ci0 += 64) {
      const int kbase = t * 256 + ci0;
#pragma unroll
      for (int q = 0; q < 4; ++q) {
        const int row = arow0 + q * 32;
        const uint4 v = *(const uint4*)(wt + (size_t)(co0 + row) * 2304 + kbase + akc * 8);
        *(uint4*)(&As[row * LDK + akc * 8]) = v;
      }
      {
        u32 vals[16];
        const int chb = ci0 + half * 32;
#pragma unroll
        for (int jj = 0; jj < 16; ++jj) {
          const float lo = valid ? xf[pixoff + (long)(chb + jj * 2) * 4096] : 0.f;
          const float hi = valid ? xf[pixoff + (long)(chb + jj * 2 + 1) * 4096] : 0.f;
          vals[jj] = (u32)f2bf(lo) | ((u32)f2bf(hi) << 16);
        }
#pragma unroll
        for (int q = 0; q < 4; ++q) {
          uint4 v; v.x = vals[q*4]; v.y = vals[q*4+1]; v.z = vals[q*4+2]; v.w = vals[q*4+3];
          *(uint4*)(&Bs[bn * LDK + half * 32 + q * 8]) = v;
        }
      }
      __syncthreads();
#pragma unroll
      for (int ks = 0; ks < 2; ++ks) {
        const int coloff = ks * 32 + (lane >> 4) * 8;
        bf16x8 af[4], bfr[4];
#pragma unroll
        for (int mi = 0; mi < 4; ++mi)
          af[mi] = *(const bf16x8*)(&As[(wm * 64 + mi * 16 + (lane & 15)) * LDK + coloff]);
#pragma unroll
        for (int ni = 0; ni < 4; ++ni)
          bfr[ni] = *(const bf16x8*)(&Bs[(wn * 64 + ni * 16 + (lane & 15)) * LDK + coloff]);
#pragma unroll
        for (int mi = 0; mi < 4; ++mi)
#pragma unroll
          for (int ni = 0; ni < 4; ++ni)
            acc[mi][ni] = __builtin_amdgcn_mfma_f32_16x16x32_bf16(af[mi], bfr[ni], acc[mi][ni], 0, 0, 0);
      }
      __syncthreads();
    }
  }
  const int pybase = p0 & 4095;
#pragma unroll
  for (int mi = 0; mi < 4; ++mi) {
#pragma unroll
    for (int j = 0; j < 4; ++j) {
      const int co = co0 + wm * 64 + mi * 16 + ((lane >> 4) << 2) + j;
      const float sh = shift[co];
      const float* awrow = aw + (size_t)(b * 8 + (co >> 5)) * 4096 + pybase;
      float* orow = out + (size_t)(b * 256 + co) * 4096 + pybase;
#pragma unroll
      for (int ni = 0; ni < 4; ++ni) {
        const int pp = wn * 64 + ni * 16 + (lane & 15);
        orow[pp] = (acc[mi][ni][j] + sh) * awrow[pp];
      }
    }
  }
}

extern "C" void kernel_launch(void* const* d_in, const int* in_sizes, int n_in,
                              void* d_out, int out_size, void* d_ws, size_t ws_size,
                              hipStream_t stream) {
  (void)in_sizes; (void)n_in; (void)out_size;
  const float* x     = (const float*)d_in[0];
  const float* guide = (const float*)d_in[1];
  const float* glw   = (const float*)d_in[2];
  const float* glb   = (const float*)d_in[3];
  const float* bias  = (const float*)d_in[4];
  const float* pw    = (const float*)d_in[5];
  const float* gamma = (const float*)d_in[6];
  const float* beta  = (const float*)d_in[7];
  const float* mean  = (const float*)d_in[8];
  const float* var   = (const float*)d_in[9];
  float* out = (float*)d_out;

  char* ws = (char*)d_ws;
  float* g     = (float*)(ws + OFF_G);
  float* aw    = (float*)(ws + OFF_AW);
  u16*   wt    = (u16*)(ws + OFF_WT);
  float* shift = (float*)(ws + OFF_SHIFT);
  u16*   xpad  = (u16*)(ws + OFF_XPAD);
  const int usexp = (ws_size >= WS_NEED) ? 1 : 0;

  g2_k<<<dim3(288), dim3(256), 0, stream>>>(pw, gamma, beta, mean, var, wt, shift,
                                            guide, glw, glb, g);
  if (usexp) {
    xpaw2_k<<<dim3(512), dim3(256), 0, stream>>>(x, g, bias, xpad, aw);
    conv8c_k<<<dim3(128, 2), dim3(512), 0, stream>>>(xpad, wt, shift, aw, out);
  } else {
    attnw_k<<<dim3(64, 16), dim3(256), 0, stream>>>(x, g, bias, aw);
    conv_fb<<<dim3(256, 2), dim3(256), 0, stream>>>(x, wt, shift, aw, out);
  }
}

// Round 15
// 70.069 us; speedup vs baseline: 1.7448x; 1.0156x over previous
//
#include <hip/hip_runtime.h>

typedef unsigned short u16;
typedef unsigned int u32;
typedef __bf16 bf16x8 __attribute__((ext_vector_type(8)));
typedef float f32x4 __attribute__((ext_vector_type(4)));

// workspace layout (bytes)
#define OFF_G      0x000000   // 8*32*256 f32   (256 KB)
#define OFF_AW     0x040000   // 8*8*4096 f32   (1 MB)
#define OFF_WT     0x140000   // 256*2304 bf16  (1.125 MB)
#define OFF_SHIFT  0x260000   // 256 f32
#define OFF_XPAD   0x2F0000   // 8*66*66*256 bf16 (zero-padded NHWC)
#define XPAD_BYTES (8u*66u*66u*256u*2u)
#define WS_NEED    ((size_t)OFF_XPAD + (size_t)XPAD_BYTES)

__device__ __forceinline__ u16 f2bf(float f) {
  union { float f; u32 u; } v; v.f = f;
  return (u16)((v.u + 0x7FFFu + ((v.u >> 16) & 1u)) >> 16);
}

__device__ __forceinline__ void gl2lds16(const u16* g, u16* l) {
  __builtin_amdgcn_global_load_lds(
      (const __attribute__((address_space(1))) void*)g,
      (__attribute__((address_space(3))) void*)l, 16, 0, 0);
}

__device__ __forceinline__ bf16x8 cvt8(const float* p) {
  const float4 a = *(const float4*)p;
  const float4 b = *(const float4*)(p + 4);
  u16 t[8];
  t[0] = f2bf(a.x); t[1] = f2bf(a.y); t[2] = f2bf(a.z); t[3] = f2bf(a.w);
  t[4] = f2bf(b.x); t[5] = f2bf(b.y); t[6] = f2bf(b.z); t[7] = f2bf(b.w);
  return *(const bf16x8*)t;
}

// ---- guide projection only (the sole prerequisite of xpw_k): 32 blocks ----
// g[b][n][e] = sum_k guide[b][n][k]*glw[e][k] + glb[e]; MFMA 16x16x32.
__global__ __launch_bounds__(256) void gp_k(
    const float* __restrict__ guide, const float* __restrict__ glw,
    const float* __restrict__ glb, float* __restrict__ g) {
  const int tid = threadIdx.x;
  const int b  = blockIdx.x >> 2;
  const int e0 = (blockIdx.x & 3) * 64;
  const int lane = tid & 63;
  const int wn   = tid >> 6;
  const int l15  = lane & 15;
  const int kq   = lane >> 4;

  const float* ga0 = guide + (size_t)b * 16384 + (size_t)l15 * 512 + kq * 8;
  const float* gb0 = glw + (size_t)(e0 + wn * 16 + l15) * 512 + kq * 8;

  f32x4 acc[2];
  acc[0] = (f32x4){0.f, 0.f, 0.f, 0.f};
  acc[1] = (f32x4){0.f, 0.f, 0.f, 0.f};
#pragma unroll
  for (int kc = 0; kc < 16; ++kc) {
    const int k0 = kc * 32;
    const bf16x8 bfr = cvt8(gb0 + k0);
#pragma unroll
    for (int mi = 0; mi < 2; ++mi) {
      const bf16x8 af = cvt8(ga0 + (size_t)mi * 16 * 512 + k0);
      acc[mi] = __builtin_amdgcn_mfma_f32_16x16x32_bf16(af, bfr, acc[mi], 0, 0, 0);
    }
  }
  const int e = e0 + wn * 16 + l15;
  const float bv = glb[e];
#pragma unroll
  for (int mi = 0; mi < 2; ++mi)
#pragma unroll
    for (int j = 0; j < 4; ++j) {
      const int n = mi * 16 + kq * 4 + j;
      g[(size_t)b * 8192 + n * 256 + e] = acc[mi][j] + bv;
    }
}

// ---- fused: blocks [0,512) = x->xpad + borders + MFMA attention;
//             blocks [512,768) = wprep (runs in xpaw's occupancy shadow) ----
__global__ __launch_bounds__(256) void xpw_k(
    const float* __restrict__ x, const float* __restrict__ g,
    const float* __restrict__ bias, u16* __restrict__ xp, float* __restrict__ aw,
    const float* __restrict__ w, const float* __restrict__ gamma,
    const float* __restrict__ beta, const float* __restrict__ mean,
    const float* __restrict__ var, u16* __restrict__ wt, float* __restrict__ shift) {
  __shared__ u16 tile[256][64];
  __shared__ u16 xT[64][256];
  const int tid = threadIdx.x;

  if (blockIdx.x >= 512) {   // ---- wprep branch (no LDS, no syncs) ----
    const int co = blockIdx.x - 512;
    const float inv = gamma[co] / sqrtf(var[co] + 1e-3f);
    float v[9];
#pragma unroll
    for (int t = 0; t < 9; ++t) v[t] = w[(size_t)co * 2304 + tid * 9 + t];
#pragma unroll
    for (int t = 0; t < 9; ++t) wt[co * 2304 + t * 256 + tid] = f2bf(v[t] * inv);
    if (tid == 0) shift[co] = beta[co] - mean[co] * inv;
    return;
  }

  const int b = blockIdx.x >> 6, y = blockIdx.x & 63;
  const int lane = tid & 63;
  const int wv   = tid >> 6;
  const int l15  = lane & 15;
  const int kq   = lane >> 4;

  // A-fragments (guide) from global f32 -> bf16 (L2-hot)
  bf16x8 af[2][2];
#pragma unroll
  for (int rep = 0; rep < 2; ++rep) {
    const int m = wv + rep * 4;
#pragma unroll
    for (int mi2 = 0; mi2 < 2; ++mi2)
      af[rep][mi2] = cvt8(g + (size_t)b * 8192 + (mi2 * 16 + l15) * 256 + m * 32 + kq * 8);
  }

  // phase 1: x row -> tile bf16
  {
    const int cb = tid >> 4, xq = tid & 15;
#pragma unroll
    for (int i = 0; i < 16; ++i) {
      const int c = i * 16 + cb;
      const float4 v = *(const float4*)(x + (size_t)(b * 256 + c) * 4096 + y * 64 + xq * 4);
      ushort4 o; o.x = f2bf(v.x); o.y = f2bf(v.y); o.z = f2bf(v.z); o.w = f2bf(v.w);
      *(ushort4*)(&tile[c][xq * 4]) = o;
    }
  }
  __syncthreads();

  // phase 2: xpad write + xT build + border zeros
  const int px = tid & 63, cg = tid >> 6;
  {
    u32 wbuf[32];
#pragma unroll
    for (int j = 0; j < 32; ++j) {
      const u16 lo = tile[cg * 64 + 2 * j][px];
      const u16 hi = tile[cg * 64 + 2 * j + 1][px];
      wbuf[j] = (u32)lo | ((u32)hi << 16);
    }
    u16* dst = xp + ((size_t)(b * 66 + y + 1) * 66 + px + 1) * 256 + cg * 64;
#pragma unroll
    for (int q = 0; q < 8; ++q) {
      uint4 v; v.x = wbuf[q * 4]; v.y = wbuf[q * 4 + 1]; v.z = wbuf[q * 4 + 2]; v.w = wbuf[q * 4 + 3];
      *(uint4*)(dst + q * 8) = v;
      const int slot = (cg * 8 + q) ^ (px & 7);   // 16B-slot XOR swizzle
      *(uint4*)(&xT[px][slot * 8]) = v;
    }
  }
  {
    uint4* rowbase = (uint4*)(xp + (size_t)(b * 66 + y + 1) * 66 * 256);
    if (tid < 32) rowbase[tid] = (uint4){0, 0, 0, 0};
    else if (tid < 64) rowbase[65 * 32 + (tid - 32)] = (uint4){0, 0, 0, 0};
    if (y == 0) {
      uint4* r0 = (uint4*)(xp + (size_t)(b * 66) * 66 * 256);
      for (int i = tid; i < 2112; i += 256) r0[i] = (uint4){0, 0, 0, 0};
    }
    if (y == 63) {
      uint4* r65 = (uint4*)(xp + (size_t)(b * 66 + 65) * 66 * 256);
      for (int i = tid; i < 2112; i += 256) r65[i] = (uint4){0, 0, 0, 0};
    }
  }
  __syncthreads();

  // phase 3: MFMA attention. scores[n][px] = sum_c g[n][c]*x[px][c]
#pragma unroll
  for (int rep = 0; rep < 2; ++rep) {
    const int m = wv + rep * 4;
    bf16x8 bfr[4];
#pragma unroll
    for (int ni2 = 0; ni2 < 4; ++ni2) {
      const int row = ni2 * 16 + l15;
      const int slot = (m * 4 + kq) ^ (row & 7);
      bfr[ni2] = *(const bf16x8*)(&xT[row][slot * 8]);
    }
    f32x4 acc[2][4];
#pragma unroll
    for (int i = 0; i < 2; ++i)
#pragma unroll
      for (int j = 0; j < 4; ++j) acc[i][j] = (f32x4){0.f, 0.f, 0.f, 0.f};
#pragma unroll
    for (int mi2 = 0; mi2 < 2; ++mi2)
#pragma unroll
      for (int ni2 = 0; ni2 < 4; ++ni2)
        acc[mi2][ni2] = __builtin_amdgcn_mfma_f32_16x16x32_bf16(af[rep][mi2], bfr[ni2], acc[mi2][ni2], 0, 0, 0);

    const float bm = bias[m];
#pragma unroll
    for (int ni2 = 0; ni2 < 4; ++ni2) {
      float v = acc[0][ni2][0];
#pragma unroll
      for (int j = 1; j < 4; ++j) v = fmaxf(v, acc[0][ni2][j]);
#pragma unroll
      for (int j = 0; j < 4; ++j) v = fmaxf(v, acc[1][ni2][j]);
      v = fmaxf(v, __shfl_xor(v, 16));
      v = fmaxf(v, __shfl_xor(v, 32));
      const float z = v * 0.17677669529663687f + bm;
      const float a = 1.f / (1.f + expf(-z));
      if (kq == 0)
        aw[(size_t)(b * 8 + m) * 4096 + y * 64 + ni2 * 16 + l15] = a;
    }
  }
}

// ---- standalone wprep (fallback path only) ----
__global__ void wprep_k(const float* __restrict__ w, const float* __restrict__ gamma,
                        const float* __restrict__ beta, const float* __restrict__ mean,
                        const float* __restrict__ var, u16* __restrict__ wt,
                        float* __restrict__ shift) {
  const int co = blockIdx.x;
  const int tid = threadIdx.x;
  const float inv = gamma[co] / sqrtf(var[co] + 1e-3f);
  float v[9];
#pragma unroll
  for (int t = 0; t < 9; ++t) v[t] = w[(size_t)co * 2304 + tid * 9 + t];
#pragma unroll
  for (int t = 0; t < 9; ++t) wt[co * 2304 + t * 256 + tid] = f2bf(v[t] * inv);
  if (tid == 0) shift[co] = beta[co] - mean[co] * inv;
}

// ---- standalone attnw (fallback path only) ----
__global__ void attnw_k(const float* __restrict__ x, const float* __restrict__ g,
                        const float* __restrict__ bias, float* __restrict__ aw) {
  const int bm = blockIdx.x;
  const int b = bm >> 3, m = bm & 7;
  const int p = blockIdx.y * 256 + threadIdx.x;
  const float* xp = x + (size_t)(b * 256 + m * 32) * 4096 + p;
  float xv[32];
#pragma unroll
  for (int c = 0; c < 32; ++c) xv[c] = xp[(size_t)c * 4096];
  const float* gv = g + b * 8192 + m * 32;
  float best = -3.4e38f;
#pragma unroll 4
  for (int n = 0; n < 32; ++n) {
    const float* grow = gv + n * 256;
    float s = 0.f;
#pragma unroll
    for (int c = 0; c < 32; ++c) s = fmaf(xv[c], grow[c], s);
    best = fmaxf(best, s);
  }
  const float z = best * 0.17677669529663687f + bias[m];
  aw[(size_t)bm * 4096 + p] = 1.f / (1.f + expf(-z));
}

// ---- conv 3x3 implicit GEMM: measured-best (44.5us, MfmaUtil 32%, 0 conflicts).
//      8-wave 128co x 256px, BK=64, triple-buffer LDS, counted vmcnt pipeline. ----
#define A_U16 8192
#define B_U16 16384
#define BUF_U16 24576

#define STAGE8(koff, bof, ab, bb) do {                                     \
    _Pragma("unroll")                                                      \
    for (int q_ = 0; q_ < 2; ++q_)                                         \
      gl2lds16(awt + (size_t)q_ * 147456 + (koff), (ab) + wv * 512 + q_ * 4096); \
    _Pragma("unroll")                                                      \
    for (int q_ = 0; q_ < 4; ++q_)                                         \
      gl2lds16(bxt + (ptrdiff_t)q_ * 16896 + (bof), (bb) + wv * 512 + q_ * 4096); \
  } while (0)

__global__ __launch_bounds__(512) void conv8c_k(
    const u16* __restrict__ xp, const u16* __restrict__ wt,
    const float* __restrict__ shift, const float* __restrict__ aw,
    float* __restrict__ out) {
  __shared__ u16 lds[3 * BUF_U16];

  const int tid  = threadIdx.x;          // 0..511
  const int lane = tid & 63;
  const int wv   = tid >> 6;             // 0..7
  const int wm   = wv >> 2;              // 0..1 (co half)
  const int wn   = wv & 3;               // 0..3 (px quarter)

  const int pxt = blockIdx.x;            // 0..127 pixel tile
  const int co0 = blockIdx.y * 128;
  const int p0  = pxt * 256;
  const int b   = pxt >> 4;
  const int y0  = (pxt & 15) * 4;

  const int sr    = tid >> 3;                    // 0..63
  const int sslot = (tid & 7) ^ (sr & 7);        // rule 21: swizzle source, linear dest
  const u16* awt = wt + (size_t)(co0 + sr) * 2304 + sslot * 8;
  const u16* bxt = xp + ((size_t)(b * 66 + y0 + 1) * 66 + sr + 1) * 256 + sslot * 8;

  u16* aR  = lds;              u16* bR  = lds + A_U16;
  u16* aN1 = lds + BUF_U16;    u16* bN1 = lds + BUF_U16 + A_U16;
  u16* aN2 = lds + 2*BUF_U16;  u16* bN2 = lds + 2*BUF_U16 + A_U16;

  const int l15 = lane & 15;
  const int sx  = lane & 7;
  const int kq  = lane >> 4;
  const int aRowB = (wm * 64 + l15) * 128;
  const int bRowB = (wn * 64 + l15) * 128;

  f32x4 acc[4][4];
#pragma unroll
  for (int i = 0; i < 4; ++i)
#pragma unroll
    for (int j = 0; j < 4; ++j) acc[i][j] = (f32x4){0.f, 0.f, 0.f, 0.f};

  STAGE8(0,  -17152,      aR,  bR);   // t=0 tap: bof = ((-1)*66 + (-1))*256
  STAGE8(64, -17152 + 64, aN1, bN1);

  int kbase = 0;   // t*256
  for (int t = 0; t < 9; ++t) {
    const int bof_c = ((t / 3 - 1) * 66 + (t % 3 - 1)) * 256;
    const int t1 = t + 1;
    const int bof_n = (t1 < 9) ? ((t1 / 3 - 1) * 66 + (t1 % 3 - 1)) * 256 : 0;
#pragma unroll
    for (int q = 0; q < 4; ++q) {
      // ---- head: chunk c's 6 loads landed (issued 2 iterations ago) ----
      if (t == 8 && q == 3) {
        asm volatile("s_waitcnt vmcnt(0)" ::: "memory");   // final chunk: drain
      } else {
        asm volatile("s_waitcnt vmcnt(6)" ::: "memory");   // c done; c+1 in flight
      }
      __builtin_amdgcn_s_barrier();
      __builtin_amdgcn_sched_barrier(0);

      // ---- stage chunk c+2 (overlaps with compute below) ----
      if ((t < 8) || (q < 2)) {
        const int ksoff = kbase + (q + 2) * 64;
        const int bsoff = (q < 2) ? (bof_c + (q + 2) * 64) : (bof_n + (q - 2) * 64);
        STAGE8(ksoff, bsoff, aN2, bN2);
      }

      // ---- compute chunk c from aR/bR ----
      const char* Ac = (const char*)aR;
      const char* Bc = (const char*)bR;
#pragma unroll
      for (int ks = 0; ks < 2; ++ks) {
        const int slotb = ((((ks << 2) | kq) ^ sx) << 4);
        bf16x8 af[4], bfr[4];
#pragma unroll
        for (int mi = 0; mi < 4; ++mi)
          af[mi] = *(const bf16x8*)(Ac + aRowB + mi * 2048 + slotb);
#pragma unroll
        for (int ni = 0; ni < 4; ++ni)
          bfr[ni] = *(const bf16x8*)(Bc + bRowB + ni * 2048 + slotb);
        __builtin_amdgcn_s_setprio(1);
#pragma unroll
        for (int mi = 0; mi < 4; ++mi)
#pragma unroll
          for (int ni = 0; ni < 4; ++ni)
            acc[mi][ni] = __builtin_amdgcn_mfma_f32_16x16x32_bf16(af[mi], bfr[ni], acc[mi][ni], 0, 0, 0);
        __builtin_amdgcn_s_setprio(0);
      }

      __builtin_amdgcn_sched_barrier(0);
      __builtin_amdgcn_s_barrier();

      u16* ta = aR; aR = aN1; aN1 = aN2; aN2 = ta;
      u16* tb = bR; bR = bN1; bN1 = bN2; bN2 = tb;
    }
    kbase += 256;
  }

  // ---- epilogue: out = (conv + shift) * aw ----
  const int pybase = p0 & 4095;
#pragma unroll
  for (int mi = 0; mi < 4; ++mi) {
#pragma unroll
    for (int j = 0; j < 4; ++j) {
      const int co = co0 + wm * 64 + mi * 16 + ((lane >> 4) << 2) + j;
      const float sh = shift[co];
      const float* awrow = aw + (size_t)(b * 8 + (co >> 5)) * 4096 + pybase;
      float* orow = out + (size_t)(b * 256 + co) * 4096 + pybase;
#pragma unroll
      for (int ni = 0; ni < 4; ++ni) {
        const int pp = wn * 64 + ni * 16 + l15;
        orow[pp] = (acc[mi][ni][j] + sh) * awrow[pp];
      }
    }
  }
}

// ---- fallback conv (f32 direct reads, predicated) if ws too small for xpad ----
#define LDK 72
__global__ __launch_bounds__(256) void conv_fb(
    const float* __restrict__ xf, const u16* __restrict__ wt,
    const float* __restrict__ shift, const float* __restrict__ aw,
    float* __restrict__ out) {
  __shared__ u16 As[128 * LDK];
  __shared__ u16 Bs[128 * LDK];
  const int tid  = threadIdx.x;
  const int lane = tid & 63;
  const int wave = tid >> 6;
  const int wm = wave >> 1, wn = wave & 1;
  const int p0  = blockIdx.x * 128;
  const int co0 = blockIdx.y * 128;
  const int b   = p0 >> 12;
  const int y0  = (p0 >> 6) & 63;
  const int bn   = tid & 127;
  const int half = tid >> 7;
  const int py = y0 + (bn >> 6);
  const int px = bn & 63;
  const long xbase = (long)b * (256L * 4096L);
  const int arow0 = tid >> 3;
  const int akc   = tid & 7;

  f32x4 acc[4][4];
#pragma unroll
  for (int i = 0; i < 4; ++i)
#pragma unroll
    for (int j = 0; j < 4; ++j) acc[i][j] = (f32x4){0.f, 0.f, 0.f, 0.f};

  for (int t = 0; t < 9; ++t) {
    const int dy = t / 3 - 1, dxx = t % 3 - 1;
    const int yy = py + dy, xg = px + dxx;
    const bool valid = ((unsigned)yy < 64u) && ((unsigned)xg < 64u);
    const long pixoff = xbase + (long)yy * 64 + xg;
    for (int ci0 = 0; ci0 < 256; ci0 += 64) {
      const int kbase = t * 256 + ci0;
#pragma unroll
      for (int q = 0; q < 4; ++q) {
        const int row = arow0 + q * 32;
        const uint4 v = *(const uint4*)(wt + (size_t)(co0 + row) * 2304 + kbase + akc * 8);
        *(uint4*)(&As[row * LDK + akc * 8]) = v;
      }
      {
        u32 vals[16];
        const int chb = ci0 + half * 32;
#pragma unroll
        for (int jj = 0; jj < 16; ++jj) {
          const float lo = valid ? xf[pixoff + (long)(chb + jj * 2) * 4096] : 0.f;
          const float hi = valid ? xf[pixoff + (long)(chb + jj * 2 + 1) * 4096] : 0.f;
          vals[jj] = (u32)f2bf(lo) | ((u32)f2bf(hi) << 16);
        }
#pragma unroll
        for (int q = 0; q < 4; ++q) {
          uint4 v; v.x = vals[q*4]; v.y = vals[q*4+1]; v.z = vals[q*4+2]; v.w = vals[q*4+3];
          *(uint4*)(&Bs[bn * LDK + half * 32 + q * 8]) = v;
        }
      }
      __syncthreads();
#pragma unroll
      for (int ks = 0; ks < 2; ++ks) {
        const int coloff = ks * 32 + (lane >> 4) * 8;
        bf16x8 af[4], bfr[4];
#pragma unroll
        for (int mi = 0; mi < 4; ++mi)
          af[mi] = *(const bf16x8*)(&As[(wm * 64 + mi * 16 + (lane & 15)) * LDK + coloff]);
#pragma unroll
        for (int ni = 0; ni < 4; ++ni)
          bfr[ni] = *(const bf16x8*)(&Bs[(wn * 64 + ni * 16 + (lane & 15)) * LDK + coloff]);
#pragma unroll
        for (int mi = 0; mi < 4; ++mi)
#pragma unroll
          for (int ni = 0; ni < 4; ++ni)
            acc[mi][ni] = __builtin_amdgcn_mfma_f32_16x16x32_bf16(af[mi], bfr[ni], acc[mi][ni], 0, 0, 0);
      }
      __syncthreads();
    }
  }
  const int pybase = p0 & 4095;
#pragma unroll
  for (int mi = 0; mi < 4; ++mi) {
#pragma unroll
    for (int j = 0; j < 4; ++j) {
      const int co = co0 + wm * 64 + mi * 16 + ((lane >> 4) << 2) + j;
      const float sh = shift[co];
      const float* awrow = aw + (size_t)(b * 8 + (co >> 5)) * 4096 + pybase;
      float* orow = out + (size_t)(b * 256 + co) * 4096 + pybase;
#pragma unroll
      for (int ni = 0; ni < 4; ++ni) {
        const int pp = wn * 64 + ni * 16 + (lane & 15);
        orow[pp] = (acc[mi][ni][j] + sh) * awrow[pp];
      }
    }
  }
}

extern "C" void kernel_launch(void* const* d_in, const int* in_sizes, int n_in,
                              void* d_out, int out_size, void* d_ws, size_t ws_size,
                              hipStream_t stream) {
  (void)in_sizes; (void)n_in; (void)out_size;
  const float* x     = (const float*)d_in[0];
  const float* guide = (const float*)d_in[1];
  const float* glw   = (const float*)d_in[2];
  const float* glb   = (const float*)d_in[3];
  const float* bias  = (const float*)d_in[4];
  const float* pw    = (const float*)d_in[5];
  const float* gamma = (const float*)d_in[6];
  const float* beta  = (const float*)d_in[7];
  const float* mean  = (const float*)d_in[8];
  const float* var   = (const float*)d_in[9];
  float* out = (float*)d_out;

  char* ws = (char*)d_ws;
  float* g     = (float*)(ws + OFF_G);
  float* aw    = (float*)(ws + OFF_AW);
  u16*   wt    = (u16*)(ws + OFF_WT);
  float* shift = (float*)(ws + OFF_SHIFT);
  u16*   xpad  = (u16*)(ws + OFF_XPAD);
  const int usexp = (ws_size >= WS_NEED) ? 1 : 0;

  gp_k<<<dim3(32), dim3(256), 0, stream>>>(guide, glw, glb, g);
  if (usexp) {
    xpw_k<<<dim3(768), dim3(256), 0, stream>>>(x, g, bias, xpad, aw,
                                               pw, gamma, beta, mean, var, wt, shift);
    conv8c_k<<<dim3(128, 2), dim3(512), 0, stream>>>(xpad, wt, shift, aw, out);
  } else {
    wprep_k<<<dim3(256), dim3(256), 0, stream>>>(pw, gamma, beta, mean, var, wt, shift);
    attnw_k<<<dim3(64, 16), dim3(256), 0, stream>>>(x, g, bias, aw);
    conv_fb<<<dim3(256, 2), dim3(256), 0, stream>>>(x, wt, shift, aw, out);
  }
}

// Round 16
// 69.730 us; speedup vs baseline: 1.7533x; 1.0049x over previous
//
#include <hip/hip_runtime.h>

typedef unsigned short u16;
typedef unsigned int u32;
typedef __bf16 bf16x8 __attribute__((ext_vector_type(8)));
typedef float f32x4 __attribute__((ext_vector_type(4)));

// workspace layout (bytes)
#define OFF_G      0x000000   // 8*32*256 f32   (256 KB)
#define OFF_AW     0x040000   // 8*8*4096 f32   (1 MB)
#define OFF_WT     0x140000   // 256*2304 bf16  (1.125 MB)
#define OFF_SHIFT  0x260000   // 256 f32
#define OFF_XPAD   0x2F0000   // 8*66*66*256 bf16 (zero-padded NHWC)
#define XPAD_BYTES (8u*66u*66u*256u*2u)
#define WS_NEED    ((size_t)OFF_XPAD + (size_t)XPAD_BYTES)

__device__ __forceinline__ u16 f2bf(float f) {
  union { float f; u32 u; } v; v.f = f;
  return (u16)((v.u + 0x7FFFu + ((v.u >> 16) & 1u)) >> 16);
}

__device__ __forceinline__ void gl2lds16(const u16* g, u16* l) {
  __builtin_amdgcn_global_load_lds(
      (const __attribute__((address_space(1))) void*)g,
      (__attribute__((address_space(3))) void*)l, 16, 0, 0);
}

__device__ __forceinline__ bf16x8 cvt8(const float* p) {
  const float4 a = *(const float4*)p;
  const float4 b = *(const float4*)(p + 4);
  u16 t[8];
  t[0] = f2bf(a.x); t[1] = f2bf(a.y); t[2] = f2bf(a.z); t[3] = f2bf(a.w);
  t[4] = f2bf(b.x); t[5] = f2bf(b.y); t[6] = f2bf(b.z); t[7] = f2bf(b.w);
  return *(const bf16x8*)t;
}

// ---- guide projection only (the sole prerequisite of xpw_k): 32 blocks ----
__global__ __launch_bounds__(256) void gp_k(
    const float* __restrict__ guide, const float* __restrict__ glw,
    const float* __restrict__ glb, float* __restrict__ g) {
  const int tid = threadIdx.x;
  const int b  = blockIdx.x >> 2;
  const int e0 = (blockIdx.x & 3) * 64;
  const int lane = tid & 63;
  const int wn   = tid >> 6;
  const int l15  = lane & 15;
  const int kq   = lane >> 4;

  const float* ga0 = guide + (size_t)b * 16384 + (size_t)l15 * 512 + kq * 8;
  const float* gb0 = glw + (size_t)(e0 + wn * 16 + l15) * 512 + kq * 8;

  f32x4 acc[2];
  acc[0] = (f32x4){0.f, 0.f, 0.f, 0.f};
  acc[1] = (f32x4){0.f, 0.f, 0.f, 0.f};
#pragma unroll
  for (int kc = 0; kc < 16; ++kc) {
    const int k0 = kc * 32;
    const bf16x8 bfr = cvt8(gb0 + k0);
#pragma unroll
    for (int mi = 0; mi < 2; ++mi) {
      const bf16x8 af = cvt8(ga0 + (size_t)mi * 16 * 512 + k0);
      acc[mi] = __builtin_amdgcn_mfma_f32_16x16x32_bf16(af, bfr, acc[mi], 0, 0, 0);
    }
  }
  const int e = e0 + wn * 16 + l15;
  const float bv = glb[e];
#pragma unroll
  for (int mi = 0; mi < 2; ++mi)
#pragma unroll
    for (int j = 0; j < 4; ++j) {
      const int n = mi * 16 + kq * 4 + j;
      g[(size_t)b * 8192 + n * 256 + e] = acc[mi][j] + bv;
    }
}

// ---- fused: blocks [0,512) = x->xpad + borders + MFMA attention;
//             blocks [512,768) = wprep (runs in xpaw's occupancy shadow) ----
__global__ __launch_bounds__(256) void xpw_k(
    const float* __restrict__ x, const float* __restrict__ g,
    const float* __restrict__ bias, u16* __restrict__ xp, float* __restrict__ aw,
    const float* __restrict__ w, const float* __restrict__ gamma,
    const float* __restrict__ beta, const float* __restrict__ mean,
    const float* __restrict__ var, u16* __restrict__ wt, float* __restrict__ shift) {
  __shared__ u16 tile[256][64];
  __shared__ u16 xT[64][256];
  const int tid = threadIdx.x;

  if (blockIdx.x >= 512) {   // ---- wprep branch (no LDS, no syncs) ----
    const int co = blockIdx.x - 512;
    const float inv = gamma[co] / sqrtf(var[co] + 1e-3f);
    float v[9];
#pragma unroll
    for (int t = 0; t < 9; ++t) v[t] = w[(size_t)co * 2304 + tid * 9 + t];
#pragma unroll
    for (int t = 0; t < 9; ++t) wt[co * 2304 + t * 256 + tid] = f2bf(v[t] * inv);
    if (tid == 0) shift[co] = beta[co] - mean[co] * inv;
    return;
  }

  const int b = blockIdx.x >> 6, y = blockIdx.x & 63;
  const int lane = tid & 63;
  const int wv   = tid >> 6;
  const int l15  = lane & 15;
  const int kq   = lane >> 4;

  bf16x8 af[2][2];
#pragma unroll
  for (int rep = 0; rep < 2; ++rep) {
    const int m = wv + rep * 4;
#pragma unroll
    for (int mi2 = 0; mi2 < 2; ++mi2)
      af[rep][mi2] = cvt8(g + (size_t)b * 8192 + (mi2 * 16 + l15) * 256 + m * 32 + kq * 8);
  }

  {
    const int cb = tid >> 4, xq = tid & 15;
#pragma unroll
    for (int i = 0; i < 16; ++i) {
      const int c = i * 16 + cb;
      const float4 v = *(const float4*)(x + (size_t)(b * 256 + c) * 4096 + y * 64 + xq * 4);
      ushort4 o; o.x = f2bf(v.x); o.y = f2bf(v.y); o.z = f2bf(v.z); o.w = f2bf(v.w);
      *(ushort4*)(&tile[c][xq * 4]) = o;
    }
  }
  __syncthreads();

  const int px = tid & 63, cg = tid >> 6;
  {
    u32 wbuf[32];
#pragma unroll
    for (int j = 0; j < 32; ++j) {
      const u16 lo = tile[cg * 64 + 2 * j][px];
      const u16 hi = tile[cg * 64 + 2 * j + 1][px];
      wbuf[j] = (u32)lo | ((u32)hi << 16);
    }
    u16* dst = xp + ((size_t)(b * 66 + y + 1) * 66 + px + 1) * 256 + cg * 64;
#pragma unroll
    for (int q = 0; q < 8; ++q) {
      uint4 v; v.x = wbuf[q * 4]; v.y = wbuf[q * 4 + 1]; v.z = wbuf[q * 4 + 2]; v.w = wbuf[q * 4 + 3];
      *(uint4*)(dst + q * 8) = v;
      const int slot = (cg * 8 + q) ^ (px & 7);   // 16B-slot XOR swizzle
      *(uint4*)(&xT[px][slot * 8]) = v;
    }
  }
  {
    uint4* rowbase = (uint4*)(xp + (size_t)(b * 66 + y + 1) * 66 * 256);
    if (tid < 32) rowbase[tid] = (uint4){0, 0, 0, 0};
    else if (tid < 64) rowbase[65 * 32 + (tid - 32)] = (uint4){0, 0, 0, 0};
    if (y == 0) {
      uint4* r0 = (uint4*)(xp + (size_t)(b * 66) * 66 * 256);
      for (int i = tid; i < 2112; i += 256) r0[i] = (uint4){0, 0, 0, 0};
    }
    if (y == 63) {
      uint4* r65 = (uint4*)(xp + (size_t)(b * 66 + 65) * 66 * 256);
      for (int i = tid; i < 2112; i += 256) r65[i] = (uint4){0, 0, 0, 0};
    }
  }
  __syncthreads();

#pragma unroll
  for (int rep = 0; rep < 2; ++rep) {
    const int m = wv + rep * 4;
    bf16x8 bfr[4];
#pragma unroll
    for (int ni2 = 0; ni2 < 4; ++ni2) {
      const int row = ni2 * 16 + l15;
      const int slot = (m * 4 + kq) ^ (row & 7);
      bfr[ni2] = *(const bf16x8*)(&xT[row][slot * 8]);
    }
    f32x4 acc[2][4];
#pragma unroll
    for (int i = 0; i < 2; ++i)
#pragma unroll
      for (int j = 0; j < 4; ++j) acc[i][j] = (f32x4){0.f, 0.f, 0.f, 0.f};
#pragma unroll
    for (int mi2 = 0; mi2 < 2; ++mi2)
#pragma unroll
      for (int ni2 = 0; ni2 < 4; ++ni2)
        acc[mi2][ni2] = __builtin_amdgcn_mfma_f32_16x16x32_bf16(af[rep][mi2], bfr[ni2], acc[mi2][ni2], 0, 0, 0);

    const float bm = bias[m];
#pragma unroll
    for (int ni2 = 0; ni2 < 4; ++ni2) {
      float v = acc[0][ni2][0];
#pragma unroll
      for (int j = 1; j < 4; ++j) v = fmaxf(v, acc[0][ni2][j]);
#pragma unroll
      for (int j = 0; j < 4; ++j) v = fmaxf(v, acc[1][ni2][j]);
      v = fmaxf(v, __shfl_xor(v, 16));
      v = fmaxf(v, __shfl_xor(v, 32));
      const float z = v * 0.17677669529663687f + bm;
      const float a = 1.f / (1.f + expf(-z));
      if (kq == 0)
        aw[(size_t)(b * 8 + m) * 4096 + y * 64 + ni2 * 16 + l15] = a;
    }
  }
}

// ---- standalone wprep (fallback path only) ----
__global__ void wprep_k(const float* __restrict__ w, const float* __restrict__ gamma,
                        const float* __restrict__ beta, const float* __restrict__ mean,
                        const float* __restrict__ var, u16* __restrict__ wt,
                        float* __restrict__ shift) {
  const int co = blockIdx.x;
  const int tid = threadIdx.x;
  const float inv = gamma[co] / sqrtf(var[co] + 1e-3f);
  float v[9];
#pragma unroll
  for (int t = 0; t < 9; ++t) v[t] = w[(size_t)co * 2304 + tid * 9 + t];
#pragma unroll
  for (int t = 0; t < 9; ++t) wt[co * 2304 + t * 256 + tid] = f2bf(v[t] * inv);
  if (tid == 0) shift[co] = beta[co] - mean[co] * inv;
}

// ---- standalone attnw (fallback path only) ----
__global__ void attnw_k(const float* __restrict__ x, const float* __restrict__ g,
                        const float* __restrict__ bias, float* __restrict__ aw) {
  const int bm = blockIdx.x;
  const int b = bm >> 3, m = bm & 7;
  const int p = blockIdx.y * 256 + threadIdx.x;
  const float* xp = x + (size_t)(b * 256 + m * 32) * 4096 + p;
  float xv[32];
#pragma unroll
  for (int c = 0; c < 32; ++c) xv[c] = xp[(size_t)c * 4096];
  const float* gv = g + b * 8192 + m * 32;
  float best = -3.4e38f;
#pragma unroll 4
  for (int n = 0; n < 32; ++n) {
    const float* grow = gv + n * 256;
    float s = 0.f;
#pragma unroll
    for (int c = 0; c < 32; ++c) s = fmaf(xv[c], grow[c], s);
    best = fmaxf(best, s);
  }
  const float z = best * 0.17677669529663687f + bias[m];
  aw[(size_t)bm * 4096 + p] = 1.f / (1.f + expf(-z));
}

// ---- conv 3x3 implicit GEMM: 8-wave 128co x 256px, triple-buffer counted-vmcnt,
//      SINGLE barrier per chunk (tail barrier dropped: 3-buf rotation makes the
//      stage target always >= 2 chunks from any in-flight reader; head barrier
//      bounds wave drift to < 1 region). 72 -> 36 barriers. ----
#define A_U16 8192
#define B_U16 16384
#define BUF_U16 24576

#define STAGE8(koff, bof, ab, bb) do {                                     \
    _Pragma("unroll")                                                      \
    for (int q_ = 0; q_ < 2; ++q_)                                         \
      gl2lds16(awt + (size_t)q_ * 147456 + (koff), (ab) + wv * 512 + q_ * 4096); \
    _Pragma("unroll")                                                      \
    for (int q_ = 0; q_ < 4; ++q_)                                         \
      gl2lds16(bxt + (ptrdiff_t)q_ * 16896 + (bof), (bb) + wv * 512 + q_ * 4096); \
  } while (0)

__global__ __launch_bounds__(512) void conv8f_k(
    const u16* __restrict__ xp, const u16* __restrict__ wt,
    const float* __restrict__ shift, const float* __restrict__ aw,
    float* __restrict__ out) {
  __shared__ u16 lds[3 * BUF_U16];

  const int tid  = threadIdx.x;          // 0..511
  const int lane = tid & 63;
  const int wv   = tid >> 6;             // 0..7
  const int wm   = wv >> 2;              // 0..1 (co half)
  const int wn   = wv & 3;               // 0..3 (px quarter)

  const int pxt = blockIdx.x;            // 0..127 pixel tile
  const int co0 = blockIdx.y * 128;
  const int p0  = pxt * 256;
  const int b   = pxt >> 4;
  const int y0  = (pxt & 15) * 4;

  const int sr    = tid >> 3;                    // 0..63
  const int sslot = (tid & 7) ^ (sr & 7);        // rule 21: swizzle source, linear dest
  const u16* awt = wt + (size_t)(co0 + sr) * 2304 + sslot * 8;
  const u16* bxt = xp + ((size_t)(b * 66 + y0 + 1) * 66 + sr + 1) * 256 + sslot * 8;

  u16* aR  = lds;              u16* bR  = lds + A_U16;
  u16* aN1 = lds + BUF_U16;    u16* bN1 = lds + BUF_U16 + A_U16;
  u16* aN2 = lds + 2*BUF_U16;  u16* bN2 = lds + 2*BUF_U16 + A_U16;

  const int l15 = lane & 15;
  const int sx  = lane & 7;
  const int kq  = lane >> 4;
  const int aRowB = (wm * 64 + l15) * 128;
  const int bRowB = (wn * 64 + l15) * 128;

  f32x4 acc[4][4];
#pragma unroll
  for (int i = 0; i < 4; ++i)
#pragma unroll
    for (int j = 0; j < 4; ++j) acc[i][j] = (f32x4){0.f, 0.f, 0.f, 0.f};

  STAGE8(0,  -17152,      aR,  bR);   // t=0 tap: bof = ((-1)*66 + (-1))*256
  STAGE8(64, -17152 + 64, aN1, bN1);

  int kbase = 0;   // t*256
  for (int t = 0; t < 9; ++t) {
    const int bof_c = ((t / 3 - 1) * 66 + (t % 3 - 1)) * 256;
    const int t1 = t + 1;
    const int bof_n = (t1 < 9) ? ((t1 / 3 - 1) * 66 + (t1 % 3 - 1)) * 256 : 0;
#pragma unroll
    for (int q = 0; q < 4; ++q) {
      // ---- single head barrier: chunk c's loads landed, all readers of the
      //      buffer staged this iteration have finished (drift < 1 region) ----
      if (t == 8 && q == 3) {
        asm volatile("s_waitcnt vmcnt(0)" ::: "memory");   // final chunk: drain
      } else {
        asm volatile("s_waitcnt vmcnt(6)" ::: "memory");   // c done; c+1 in flight
      }
      __builtin_amdgcn_s_barrier();
      __builtin_amdgcn_sched_barrier(0);

      // ---- stage chunk c+2 (overlaps with compute below) ----
      if ((t < 8) || (q < 2)) {
        const int ksoff = kbase + (q + 2) * 64;
        const int bsoff = (q < 2) ? (bof_c + (q + 2) * 64) : (bof_n + (q - 2) * 64);
        STAGE8(ksoff, bsoff, aN2, bN2);
      }

      // ---- compute chunk c from aR/bR ----
      const char* Ac = (const char*)aR;
      const char* Bc = (const char*)bR;
#pragma unroll
      for (int ks = 0; ks < 2; ++ks) {
        const int slotb = ((((ks << 2) | kq) ^ sx) << 4);
        bf16x8 af[4], bfr[4];
#pragma unroll
        for (int mi = 0; mi < 4; ++mi)
          af[mi] = *(const bf16x8*)(Ac + aRowB + mi * 2048 + slotb);
#pragma unroll
        for (int ni = 0; ni < 4; ++ni)
          bfr[ni] = *(const bf16x8*)(Bc + bRowB + ni * 2048 + slotb);
        __builtin_amdgcn_s_setprio(1);
#pragma unroll
        for (int mi = 0; mi < 4; ++mi)
#pragma unroll
          for (int ni = 0; ni < 4; ++ni)
            acc[mi][ni] = __builtin_amdgcn_mfma_f32_16x16x32_bf16(af[mi], bfr[ni], acc[mi][ni], 0, 0, 0);
        __builtin_amdgcn_s_setprio(0);
      }

      u16* ta = aR; aR = aN1; aN1 = aN2; aN2 = ta;
      u16* tb = bR; bR = bN1; bN1 = bN2; bN2 = tb;
    }
    kbase += 256;
  }

  // ---- epilogue: out = (conv + shift) * aw ----
  const int pybase = p0 & 4095;
#pragma unroll
  for (int mi = 0; mi < 4; ++mi) {
#pragma unroll
    for (int j = 0; j < 4; ++j) {
      const int co = co0 + wm * 64 + mi * 16 + ((lane >> 4) << 2) + j;
      const float sh = shift[co];
      const float* awrow = aw + (size_t)(b * 8 + (co >> 5)) * 4096 + pybase;
      float* orow = out + (size_t)(b * 256 + co) * 4096 + pybase;
#pragma unroll
      for (int ni = 0; ni < 4; ++ni) {
        const int pp = wn * 64 + ni * 16 + l15;
        orow[pp] = (acc[mi][ni][j] + sh) * awrow[pp];
      }
    }
  }
}

// ---- fallback conv (f32 direct reads, predicated) if ws too small for xpad ----
#define LDK 72
__global__ __launch_bounds__(256) void conv_fb(
    const float* __restrict__ xf, const u16* __restrict__ wt,
    const float* __restrict__ shift, const float* __restrict__ aw,
    float* __restrict__ out) {
  __shared__ u16 As[128 * LDK];
  __shared__ u16 Bs[128 * LDK];
  const int tid  = threadIdx.x;
  const int lane = tid & 63;
  const int wave = tid >> 6;
  const int wm = wave >> 1, wn = wave & 1;
  const int p0  = blockIdx.x * 128;
  const int co0 = blockIdx.y * 128;
  const int b   = p0 >> 12;
  const int y0  = (p0 >> 6) & 63;
  const int bn   = tid & 127;
  const int half = tid >> 7;
  const int py = y0 + (bn >> 6);
  const int px = bn & 63;
  const long xbase = (long)b * (256L * 4096L);
  const int arow0 = tid >> 3;
  const int akc   = tid & 7;

  f32x4 acc[4][4];
#pragma unroll
  for (int i = 0; i < 4; ++i)
#pragma unroll
    for (int j = 0; j < 4; ++j) acc[i][j] = (f32x4){0.f, 0.f, 0.f, 0.f};

  for (int t = 0; t < 9; ++t) {
    const int dy = t / 3 - 1, dxx = t % 3 - 1;
    const int yy = py + dy, xg = px + dxx;
    const bool valid = ((unsigned)yy < 64u) && ((unsigned)xg < 64u);
    const long pixoff = xbase + (long)yy * 64 + xg;
    for (int ci0 = 0; ci0 < 256; ci0 += 64) {
      const int kbase = t * 256 + ci0;
#pragma unroll
      for (int q = 0; q < 4; ++q) {
        const int row = arow0 + q * 32;
        const uint4 v = *(const uint4*)(wt + (size_t)(co0 + row) * 2304 + kbase + akc * 8);
        *(uint4*)(&As[row * LDK + akc * 8]) = v;
      }
      {
        u32 vals[16];
        const int chb = ci0 + half * 32;
#pragma unroll
        for (int jj = 0; jj < 16; ++jj) {
          const float lo = valid ? xf[pixoff + (long)(chb + jj * 2) * 4096] : 0.f;
          const float hi = valid ? xf[pixoff + (long)(chb + jj * 2 + 1) * 4096] : 0.f;
          vals[jj] = (u32)f2bf(lo) | ((u32)f2bf(hi) << 16);
        }
#pragma unroll
        for (int q = 0; q < 4; ++q) {
          uint4 v; v.x = vals[q*4]; v.y = vals[q*4+1]; v.z = vals[q*4+2]; v.w = vals[q*4+3];
          *(uint4*)(&Bs[bn * LDK + half * 32 + q * 8]) = v;
        }
      }
      __syncthreads();
#pragma unroll
      for (int ks = 0; ks < 2; ++ks) {
        const int coloff = ks * 32 + (lane >> 4) * 8;
        bf16x8 af[4], bfr[4];
#pragma unroll
        for (int mi = 0; mi < 4; ++mi)
          af[mi] = *(const bf16x8*)(&As[(wm * 64 + mi * 16 + (lane & 15)) * LDK + coloff]);
#pragma unroll
        for (int ni = 0; ni < 4; ++ni)
          bfr[ni] = *(const bf16x8*)(&Bs[(wn * 64 + ni * 16 + (lane & 15)) * LDK + coloff]);
#pragma unroll
        for (int mi = 0; mi < 4; ++mi)
#pragma unroll
          for (int ni = 0; ni < 4; ++ni)
            acc[mi][ni] = __builtin_amdgcn_mfma_f32_16x16x32_bf16(af[mi], bfr[ni], acc[mi][ni], 0, 0, 0);
      }
      __syncthreads();
    }
  }
  const int pybase = p0 & 4095;
#pragma unroll
  for (int mi = 0; mi < 4; ++mi) {
#pragma unroll
    for (int j = 0; j < 4; ++j) {
      const int co = co0 + wm * 64 + mi * 16 + ((lane >> 4) << 2) + j;
      const float sh = shift[co];
      const float* awrow = aw + (size_t)(b * 8 + (co >> 5)) * 4096 + pybase;
      float* orow = out + (size_t)(b * 256 + co) * 4096 + pybase;
#pragma unroll
      for (int ni = 0; ni < 4; ++ni) {
        const int pp = wn * 64 + ni * 16 + (lane & 15);
        orow[pp] = (acc[mi][ni][j] + sh) * awrow[pp];
      }
    }
  }
}

extern "C" void kernel_launch(void* const* d_in, const int* in_sizes, int n_in,
                              void* d_out, int out_size, void* d_ws, size_t ws_size,
                              hipStream_t stream) {
  (void)in_sizes; (void)n_in; (void)out_size;
  const float* x     = (const float*)d_in[0];
  const float* guide = (const float*)d_in[1];
  const float* glw   = (const float*)d_in[2];
  const float* glb   = (const float*)d_in[3];
  const float* bias  = (const float*)d_in[4];
  const float* pw    = (const float*)d_in[5];
  const float* gamma = (const float*)d_in[6];
  const float* beta  = (const float*)d_in[7];
  const float* mean  = (const float*)d_in[8];
  const float* var   = (const float*)d_in[9];
  float* out = (float*)d_out;

  char* ws = (char*)d_ws;
  float* g     = (float*)(ws + OFF_G);
  float* aw    = (float*)(ws + OFF_AW);
  u16*   wt    = (u16*)(ws + OFF_WT);
  float* shift = (float*)(ws + OFF_SHIFT);
  u16*   xpad  = (u16*)(ws + OFF_XPAD);
  const int usexp = (ws_size >= WS_NEED) ? 1 : 0;

  gp_k<<<dim3(32), dim3(256), 0, stream>>>(guide, glw, glb, g);
  if (usexp) {
    xpw_k<<<dim3(768), dim3(256), 0, stream>>>(x, g, bias, xpad, aw,
                                               pw, gamma, beta, mean, var, wt, shift);
    conv8f_k<<<dim3(128, 2), dim3(512), 0, stream>>>(xpad, wt, shift, aw, out);
  } else {
    wprep_k<<<dim3(256), dim3(256), 0, stream>>>(pw, gamma, beta, mean, var, wt, shift);
    attnw_k<<<dim3(64, 16), dim3(256), 0, stream>>>(x, g, bias, aw);
    conv_fb<<<dim3(256, 2), dim3(256), 0, stream>>>(x, wt, shift, aw, out);
  }
}